// Round 1
// baseline (11104.415 us; speedup 1.0000x reference)
//
#include <hip/hip_runtime.h>
#include <hip/hip_bf16.h>

#define B_ 8
#define T_ 2048
#define D_ 1024
#define W_ 64
#define LN_EPS 1e-5f

typedef __attribute__((ext_vector_type(8))) short bf16x8;
typedef __attribute__((ext_vector_type(4))) float f32x4;
typedef unsigned short ushort_t;

__device__ __forceinline__ ushort_t f32_to_bf16(float f) {
    union { float ff; unsigned u; } c; c.ff = f;
    unsigned r = (c.u + 0x7fffu + ((c.u >> 16) & 1u)) >> 16;
    return (ushort_t)r;
}

__device__ __forceinline__ float tanh_fast(float x) {
    float xx = fminf(fmaxf(x, -20.f), 20.f);
    float e = __expf(2.f * xx);
    return 1.f - 2.f / (e + 1.f);
}

// ---------- K0: feature -> bf16 ----------
__global__ void cvt_feat(const float* __restrict__ f, ushort_t* __restrict__ o, int n) {
    int i = blockIdx.x * blockDim.x + threadIdx.x;
    if (i < n) o[i] = f32_to_bf16(f[i]);
}

// ---------- K1: wqT[n][k] = bf16(wq[k][n]) ----------
__global__ void cvt_wqT(const float* __restrict__ wq, ushort_t* __restrict__ o) {
    __shared__ float tile[64][65];
    int bi = blockIdx.x;             // k block
    int bj = blockIdx.y;             // n block
    int tid = threadIdx.x;           // 256
    int c = tid & 63, r4 = tid >> 6;
    for (int it = 0; it < 16; ++it) {
        int r = it * 4 + r4;
        tile[r][c] = wq[(size_t)(bi * 64 + r) * D_ + bj * 64 + c];
    }
    __syncthreads();
    for (int it = 0; it < 16; ++it) {
        int r = it * 4 + r4;  // n offset within tile
        o[(size_t)(bj * 64 + r) * D_ + bi * 64 + c] = f32_to_bf16(tile[c][r]);
    }
}

// ---------- K2: qw = (featbf @ wqT^T + wq_b) * w2_w  (MFMA bf16) ----------
// A: M x 1024 row-major bf16, BT: 1024 x 1024 (n-major) bf16. Tile 128x64, block=256 (4 waves 2x2).
__global__ __launch_bounds__(256) void gemm_qw(
        const ushort_t* __restrict__ A, const ushort_t* __restrict__ BT,
        const float* __restrict__ wqb, const float* __restrict__ w2w,
        float* __restrict__ out) {
    const int K = 1024;
    __shared__ ushort_t Al[128][48];  // stride 48 shorts = 96B (16B-aligned, breaks pow2 banks)
    __shared__ ushort_t Bl[64][48];
    int tid = threadIdx.x;
    int lane = tid & 63, wv = tid >> 6;
    int wm = wv >> 1, wn = wv & 1;
    int m0 = blockIdx.x * 128, n0 = blockIdx.y * 64;
    int mrow = lane & 15, quad = lane >> 4;
    f32x4 acc[4][2] = {};
    for (int k0 = 0; k0 < K; k0 += 32) {
#pragma unroll
        for (int rep = 0; rep < 2; ++rep) {
            int idx = rep * 256 + tid;
            int r = idx >> 2, cp = (idx & 3) * 8;
            *(bf16x8*)&Al[r][cp] = *(const bf16x8*)&A[(size_t)(m0 + r) * K + k0 + cp];
        }
        {
            int r = tid >> 2, cp = (tid & 3) * 8;
            *(bf16x8*)&Bl[r][cp] = *(const bf16x8*)&BT[(size_t)(n0 + r) * K + k0 + cp];
        }
        __syncthreads();
        bf16x8 af[4], bfr[2];
#pragma unroll
        for (int ms = 0; ms < 4; ++ms) af[ms] = *(bf16x8*)&Al[wm * 64 + ms * 16 + mrow][quad * 8];
#pragma unroll
        for (int ns = 0; ns < 2; ++ns) bfr[ns] = *(bf16x8*)&Bl[wn * 32 + ns * 16 + mrow][quad * 8];
#pragma unroll
        for (int ms = 0; ms < 4; ++ms)
#pragma unroll
            for (int ns = 0; ns < 2; ++ns)
                acc[ms][ns] = __builtin_amdgcn_mfma_f32_16x16x32_bf16(af[ms], bfr[ns], acc[ms][ns], 0, 0, 0);
        __syncthreads();
    }
    // epilogue: C layout col=lane&15, row=quad*4+r
#pragma unroll
    for (int ns = 0; ns < 2; ++ns) {
        int n = n0 + wn * 32 + ns * 16 + mrow;
        float scale = w2w[n], bias = wqb[n];
#pragma unroll
        for (int ms = 0; ms < 4; ++ms) {
#pragma unroll
            for (int r = 0; r < 4; ++r) {
                int m = m0 + wm * 64 + ms * 16 + quad * 4 + r;
                out[(size_t)m * D_ + n] = (acc[ms][ns][r] + bias) * scale;
            }
        }
    }
}

// ---------- K2-fallback: fp32 tiled GEMM (if ws too small for bf16 copies) ----------
__global__ __launch_bounds__(256) void gemm_qw_f32(
        const float* __restrict__ A, const float* __restrict__ Bw,
        const float* __restrict__ wqb, const float* __restrict__ w2w,
        float* __restrict__ out) {
    __shared__ float As[64][17];
    __shared__ float Bs[16][65];
    int tx = threadIdx.x & 15, ty = threadIdx.x >> 4;
    int m0 = blockIdx.x * 64, n0 = blockIdx.y * 64;
    float acc[4][4] = {};
    for (int k0 = 0; k0 < 1024; k0 += 16) {
#pragma unroll
        for (int i = 0; i < 4; ++i) {
            int idx = i * 256 + threadIdx.x;
            int r = idx >> 4, c = idx & 15;
            As[r][c] = A[(size_t)(m0 + r) * 1024 + k0 + c];
        }
#pragma unroll
        for (int i = 0; i < 4; ++i) {
            int idx = i * 256 + threadIdx.x;
            int r = idx >> 6, c = idx & 63;
            Bs[r][c] = Bw[(size_t)(k0 + r) * 1024 + n0 + c];
        }
        __syncthreads();
#pragma unroll
        for (int kk = 0; kk < 16; ++kk)
#pragma unroll
            for (int i = 0; i < 4; ++i)
#pragma unroll
                for (int j = 0; j < 4; ++j)
                    acc[i][j] = fmaf(As[ty * 4 + i][kk], Bs[kk][tx * 4 + j], acc[i][j]);
        __syncthreads();
    }
#pragma unroll
    for (int i = 0; i < 4; ++i)
#pragma unroll
        for (int j = 0; j < 4; ++j) {
            int n = n0 + tx * 4 + j;
            out[(size_t)(m0 + ty * 4 + i) * 1024 + n] = (acc[i][j] + wqb[n]) * w2w[n];
        }
}

// ---------- K3: sequential attention scan + fused tanh-gate + LayerNorm ----------
// One block (1024 threads) per batch. Thread d owns column d of the 64-row window (registers).
// d_out doubles as qw input: row t is read (prefetched at step t-1) before being overwritten at step t.
__global__ __launch_bounds__(1024) void scan_kernel(
        const float* __restrict__ feat, float* outqw,
        const float* __restrict__ lng, const float* __restrict__ lnb) {
    const int b = blockIdx.x;
    const int tid = threadIdx.x;
    const int lane = tid & 63, wv = tid >> 6;
    __shared__ float swave[16][64];
    __shared__ __align__(16) float alphaL[64];
    __shared__ float red[16][2];
    const float g = lng[tid], bb = lnb[tid];
    const size_t base = (size_t)b * T_ * D_;
    const int l4 = lane & 15;
    const int rev4l = ((l4 & 1) << 3) | ((l4 & 2) << 1) | ((l4 & 4) >> 1) | ((l4 & 8) >> 3);

    // ---- prologue: rows 0..63 : v_local = feature ----
    for (int t = 0; t < W_; ++t) {
        float f = feat[base + t * D_ + tid];
        float th = tanh_fast(f);
        float y = th * f + f;
        float s1 = y, s2 = y * y;
#pragma unroll
        for (int m = 1; m < 64; m <<= 1) { s1 += __shfl_xor(s1, m, 64); s2 += __shfl_xor(s2, m, 64); }
        if (lane == 0) { red[wv][0] = s1; red[wv][1] = s2; }
        __syncthreads();
        float mu = 0.f, m2 = 0.f;
#pragma unroll
        for (int i = 0; i < 16; ++i) { mu += red[i][0]; m2 += red[i][1]; }
        mu *= (1.f / D_); m2 *= (1.f / D_);
        float rv = rsqrtf(fmaxf(m2 - mu * mu, 0.f) + LN_EPS);
        outqw[base + t * D_ + tid] = (y - mu) * rv * g + bb;
        __syncthreads();
    }

    // ---- init window registers: colbuf[w] = feature[b][w][d] (compile-time indices) ----
    float colbuf[64];
#pragma unroll
    for (int w = 0; w < 64; ++w) colbuf[w] = feat[base + w * D_ + tid];

    // prefetch t=64
    float qn = outqw[base + (size_t)W_ * D_ + tid];
    float fn = feat[base + (size_t)W_ * D_ + tid];

    for (int t0 = W_; t0 < T_; t0 += 4) {
#pragma unroll
        for (int s = 0; s < 4; ++s) {
            const int t = t0 + s;
            float qd = qn, fd = fn;
            int tp = (t + 1 < T_) ? (t + 1) : t;
            qn = outqw[base + (size_t)tp * D_ + tid];
            fn = feat[base + (size_t)tp * D_ + tid];

            // ---- scores: transpose-reduce in 4 groups of 16 values ----
#pragma unroll
            for (int gI = 0; gI < 4; ++gI) {
                float cur[16];
#pragma unroll
                for (int i = 0; i < 16; ++i) cur[i] = colbuf[gI * 16 + i] * qd;
                int n = 16;
#pragma unroll
                for (int k = 0; k < 4; ++k) {
                    int m = 1 << k;
                    bool up = (lane & m) != 0;
                    n >>= 1;
#pragma unroll
                    for (int i = 0; i < n; ++i) {
                        float give = up ? cur[i] : cur[i + n];
                        float keep = up ? cur[i + n] : cur[i];
                        cur[i] = keep + __shfl_xor(give, m, 64);
                    }
                }
                float c0 = cur[0];
                c0 += __shfl_xor(c0, 16, 64);
                c0 += __shfl_xor(c0, 32, 64);
                if (lane < 16) swave[wv][gI * 16 + rev4l] = c0;  // natural slot order
            }
            __syncthreads();

            // ---- softmax over 64 dots + zero-row (dot=0); w2_b uniform -> cancels ----
            if (wv == 0) {
                float sc = 0.f;
#pragma unroll
                for (int i = 0; i < 16; ++i) sc += swave[i][lane];
                float mx = sc;
#pragma unroll
                for (int m = 1; m < 64; m <<= 1) mx = fmaxf(mx, __shfl_xor(mx, m, 64));
                mx = fmaxf(mx, 0.f);
                float e = __expf(sc - mx);
                float tot = e;
#pragma unroll
                for (int m = 1; m < 64; m <<= 1) tot += __shfl_xor(tot, m, 64);
                tot += __expf(0.f - mx);  // zero-row term
                alphaL[lane] = e / tot;
            }
            __syncthreads();

            // ---- v = sum_w alpha[w] * colbuf[w] (pure local FMAs) ----
            float a0 = 0.f, a1 = 0.f, a2 = 0.f, a3 = 0.f;
#pragma unroll
            for (int i = 0; i < 16; ++i) {
                float4 aa = *((const float4*)alphaL + i);
                a0 = fmaf(aa.x, colbuf[4 * i + 0], a0);
                a1 = fmaf(aa.y, colbuf[4 * i + 1], a1);
                a2 = fmaf(aa.z, colbuf[4 * i + 2], a2);
                a3 = fmaf(aa.w, colbuf[4 * i + 3], a3);
            }
            float v = (a0 + a1) + (a2 + a3);
            colbuf[s] = v;  // replace oldest (slot s within this 4-group)

            // ---- fused epilogue: y = tanh(v)*f + f ; LayerNorm ----
            float th = tanh_fast(v);
            float y = th * fd + fd;
            float s1 = y, s2 = y * y;
#pragma unroll
            for (int m = 1; m < 64; m <<= 1) { s1 += __shfl_xor(s1, m, 64); s2 += __shfl_xor(s2, m, 64); }
            if (lane == 0) { red[wv][0] = s1; red[wv][1] = s2; }
            __syncthreads();
            float mu = 0.f, m2 = 0.f;
#pragma unroll
            for (int i = 0; i < 16; ++i) { mu += red[i][0]; m2 += red[i][1]; }
            mu *= (1.f / D_); m2 *= (1.f / D_);
            float rv = rsqrtf(fmaxf(m2 - mu * mu, 0.f) + LN_EPS);
            outqw[base + (size_t)t * D_ + tid] = (y - mu) * rv * g + bb;
            __syncthreads();
        }
        // rotate window registers by 4 (keep oldest at index 0)
        float tp0 = colbuf[0], tp1 = colbuf[1], tp2 = colbuf[2], tp3 = colbuf[3];
#pragma unroll
        for (int wj = 0; wj < 60; ++wj) colbuf[wj] = colbuf[wj + 4];
        colbuf[60] = tp0; colbuf[61] = tp1; colbuf[62] = tp2; colbuf[63] = tp3;
    }
}

extern "C" void kernel_launch(void* const* d_in, const int* in_sizes, int n_in,
                              void* d_out, int out_size, void* d_ws, size_t ws_size,
                              hipStream_t stream) {
    const float* feature = (const float*)d_in[0];
    const float* wq_w    = (const float*)d_in[1];
    const float* wq_b    = (const float*)d_in[2];
    const float* w2_w    = (const float*)d_in[3];
    // d_in[4] = w2_b: uniform additive logit -> softmax-invariant, unused
    const float* ln_g    = (const float*)d_in[5];
    const float* ln_b    = (const float*)d_in[6];
    float* out = (float*)d_out;

    const int ntot = B_ * T_ * D_;
    const size_t need = ((size_t)ntot + (size_t)D_ * D_) * sizeof(ushort_t);

    if (ws_size >= need) {
        ushort_t* featbf = (ushort_t*)d_ws;
        ushort_t* wqT = featbf + (size_t)ntot;
        cvt_feat<<<(ntot + 255) / 256, 256, 0, stream>>>(feature, featbf, ntot);
        cvt_wqT<<<dim3(16, 16), 256, 0, stream>>>(wq_w, wqT);
        gemm_qw<<<dim3(128, 16), 256, 0, stream>>>(featbf, wqT, wq_b, w2_w, out);
    } else {
        gemm_qw_f32<<<dim3(256, 16), 256, 0, stream>>>(feature, wq_w, wq_b, w2_w, out);
    }
    scan_kernel<<<8, 1024, 0, stream>>>(feature, out, ln_g, ln_b);
}

// Round 2
// 2800.882 us; speedup vs baseline: 3.9646x; 3.9646x over previous
//
#include <hip/hip_runtime.h>
#include <hip/hip_bf16.h>

#define B_ 8
#define T_ 2048
#define D_ 1024
#define W_ 64
#define LN_EPS 1e-5f

typedef __attribute__((ext_vector_type(8))) short bf16x8;
typedef __attribute__((ext_vector_type(4))) float f32x4;
typedef unsigned short ushort_t;

__device__ __forceinline__ ushort_t f32_to_bf16(float f) {
    union { float ff; unsigned u; } c; c.ff = f;
    unsigned r = (c.u + 0x7fffu + ((c.u >> 16) & 1u)) >> 16;
    return (ushort_t)r;
}
__device__ __forceinline__ float bf16_to_f32(ushort_t h) {
    union { unsigned u; float f; } c; c.u = ((unsigned)h) << 16; return c.f;
}
__device__ __forceinline__ float tanh_fast(float x) {
    float xx = fminf(fmaxf(x, -20.f), 20.f);
    float e = __expf(2.f * xx);
    return 1.f - 2.f / (e + 1.f);
}
template <int P>
__device__ __forceinline__ float swz(float v) {
    return __int_as_float(__builtin_amdgcn_ds_swizzle(__float_as_int(v), P));
}
__device__ __forceinline__ float readlane_f(float v, int l) {
    return __int_as_float(__builtin_amdgcn_readlane(__float_as_int(v), l));
}
// sum of x across all 64 lanes, returned as wave-uniform value
__device__ __forceinline__ float sum64_u(float x) {
    x += swz<0x041F>(x);  // xor 1
    x += swz<0x081F>(x);  // xor 2
    x += swz<0x101F>(x);  // xor 4
    x += swz<0x201F>(x);  // xor 8
    x += swz<0x401F>(x);  // xor 16
    return readlane_f(x, 0) + readlane_f(x, 32);
}

// ---------- K0: feature -> bf16 ----------
__global__ void cvt_feat(const float* __restrict__ f, ushort_t* __restrict__ o, int n) {
    int i = blockIdx.x * blockDim.x + threadIdx.x;
    if (i < n) o[i] = f32_to_bf16(f[i]);
}

// ---------- K1: wqT[n][k] = bf16(wq[k][n]) ----------
__global__ void cvt_wqT(const float* __restrict__ wq, ushort_t* __restrict__ o) {
    __shared__ float tile[64][65];
    int bi = blockIdx.x, bj = blockIdx.y, tid = threadIdx.x;
    int c = tid & 63, r4 = tid >> 6;
    for (int it = 0; it < 16; ++it) {
        int r = it * 4 + r4;
        tile[r][c] = wq[(size_t)(bi * 64 + r) * D_ + bj * 64 + c];
    }
    __syncthreads();
    for (int it = 0; it < 16; ++it) {
        int r = it * 4 + r4;
        o[(size_t)(bj * 64 + r) * D_ + bi * 64 + c] = f32_to_bf16(tile[c][r]);
    }
}

// ---------- K2: qw = (featbf @ wqT^T + wq_b) * w2_w  (MFMA bf16) ----------
__global__ __launch_bounds__(256) void gemm_qw(
        const ushort_t* __restrict__ A, const ushort_t* __restrict__ BT,
        const float* __restrict__ wqb, const float* __restrict__ w2w,
        float* __restrict__ out) {
    const int K = 1024;
    __shared__ ushort_t Al[128][48];
    __shared__ ushort_t Bl[64][48];
    int tid = threadIdx.x;
    int lane = tid & 63, wv = tid >> 6;
    int wm = wv >> 1, wn = wv & 1;
    int m0 = blockIdx.x * 128, n0 = blockIdx.y * 64;
    int mrow = lane & 15, quad = lane >> 4;
    f32x4 acc[4][2] = {};
    for (int k0 = 0; k0 < K; k0 += 32) {
#pragma unroll
        for (int rep = 0; rep < 2; ++rep) {
            int idx = rep * 256 + tid;
            int r = idx >> 2, cp = (idx & 3) * 8;
            *(bf16x8*)&Al[r][cp] = *(const bf16x8*)&A[(size_t)(m0 + r) * K + k0 + cp];
        }
        {
            int r = tid >> 2, cp = (tid & 3) * 8;
            *(bf16x8*)&Bl[r][cp] = *(const bf16x8*)&BT[(size_t)(n0 + r) * K + k0 + cp];
        }
        __syncthreads();
        bf16x8 af[4], bfr[2];
#pragma unroll
        for (int ms = 0; ms < 4; ++ms) af[ms] = *(bf16x8*)&Al[wm * 64 + ms * 16 + mrow][quad * 8];
#pragma unroll
        for (int ns = 0; ns < 2; ++ns) bfr[ns] = *(bf16x8*)&Bl[wn * 32 + ns * 16 + mrow][quad * 8];
#pragma unroll
        for (int ms = 0; ms < 4; ++ms)
#pragma unroll
            for (int ns = 0; ns < 2; ++ns)
                acc[ms][ns] = __builtin_amdgcn_mfma_f32_16x16x32_bf16(af[ms], bfr[ns], acc[ms][ns], 0, 0, 0);
        __syncthreads();
    }
#pragma unroll
    for (int ns = 0; ns < 2; ++ns) {
        int n = n0 + wn * 32 + ns * 16 + mrow;
        float scale = w2w[n], bias = wqb[n];
#pragma unroll
        for (int ms = 0; ms < 4; ++ms) {
#pragma unroll
            for (int r = 0; r < 4; ++r) {
                int m = m0 + wm * 64 + ms * 16 + quad * 4 + r;
                out[(size_t)m * D_ + n] = (acc[ms][ns][r] + bias) * scale;
            }
        }
    }
}

// ---------- K3: transpose first 64 feature rows: fT32/fTh/fTl [b][d][w] ----------
__global__ void featT_kernel(const float* __restrict__ feat, float* __restrict__ fT32,
                             ushort_t* __restrict__ fTh, ushort_t* __restrict__ fTl) {
    __shared__ float tile[64][65];
    int d0 = blockIdx.x * 64, b = blockIdx.y, tid = threadIdx.x;
    int c = tid & 63, r4 = tid >> 6;
#pragma unroll
    for (int it = 0; it < 16; ++it) {
        int r = it * 4 + r4;  // window row w
        tile[r][c] = feat[((size_t)b * T_ + r) * D_ + d0 + c];
    }
    __syncthreads();
#pragma unroll
    for (int it = 0; it < 16; ++it) {
        int r = it * 4 + r4;  // d offset
        float v = tile[c][r]; // = feature[b][w=c][d0+r]
        size_t o = ((size_t)b * D_ + d0 + r) * 64 + c;
        fT32[o] = v;
        ushort_t h = f32_to_bf16(v);
        fTh[o] = h;
        fTl[o] = f32_to_bf16(v - bf16_to_f32(h));
    }
}

// ---------- K4: S0[b][t][w] = qw[b][t]·F0[b][w]  (fp32, stored as bf16 hi/lo) ----------
__global__ __launch_bounds__(256) void s0_gemm(
        const float* __restrict__ qw, const float* __restrict__ fT32,
        ushort_t* __restrict__ S0h, ushort_t* __restrict__ S0l) {
    __shared__ float As[64][17];
    __shared__ float Bs[16][65];
    int b = blockIdx.y;
    int t0 = 64 + blockIdx.x * 64;
    int tx = threadIdx.x & 15, ty = threadIdx.x >> 4;
    float acc[4][4] = {};
    for (int k0 = 0; k0 < D_; k0 += 16) {
#pragma unroll
        for (int i = 0; i < 4; ++i) {
            int idx = i * 256 + threadIdx.x;
            int r = idx >> 4, c = idx & 15;
            As[r][c] = qw[((size_t)b * T_ + t0 + r) * D_ + k0 + c];
        }
#pragma unroll
        for (int i = 0; i < 4; ++i) {
            int idx = i * 256 + threadIdx.x;
            int r = idx >> 6, c = idx & 63;
            Bs[r][c] = fT32[((size_t)b * D_ + k0 + r) * 64 + c];
        }
        __syncthreads();
#pragma unroll
        for (int kk = 0; kk < 16; ++kk)
#pragma unroll
            for (int i = 0; i < 4; ++i)
#pragma unroll
                for (int j = 0; j < 4; ++j)
                    acc[i][j] = fmaf(As[ty * 4 + i][kk], Bs[kk][tx * 4 + j], acc[i][j]);
        __syncthreads();
    }
#pragma unroll
    for (int i = 0; i < 4; ++i)
#pragma unroll
        for (int j = 0; j < 4; ++j) {
            float sc = acc[i][j];
            ushort_t h = f32_to_bf16(sc);
            size_t o = ((size_t)b * T_ + t0 + ty * 4 + i) * 64 + tx * 4 + j;
            S0h[o] = h;
            S0l[o] = f32_to_bf16(sc - bf16_to_f32(h));
        }
}

// ---------- K5: sequential core in 64-dim coefficient space (1 wave per batch) ----------
__global__ __launch_bounds__(64) void core_kernel(
        const ushort_t* __restrict__ S0h, const ushort_t* __restrict__ S0l,
        float* __restrict__ gamma) {
    const int b = blockIdx.x;
    const int lane = threadIdx.x;
    const int n16 = lane & 15, quad = lane >> 4;
    __shared__ float ULDS[64 * 67];
    __shared__ __align__(16) float ALDS[64];
    __shared__ ushort_t CHb[2][64 * 72];
    __shared__ ushort_t CLb[2][64 * 72];

    float X1[64], CPw[64], CWw[64];
#pragma unroll
    for (int l = 0; l < 64; ++l) { CPw[l] = (l == lane) ? 1.f : 0.f; CWw[l] = 0.f; }
#pragma unroll
    for (int j = 0; j < 72; ++j) {
        CHb[0][lane * 72 + j] = (j == lane) ? (ushort_t)0x3F80 : (ushort_t)0;
        CLb[0][lane * 72 + j] = 0;
    }
    // single wave: no barrier needed (DS pipe is in-order per wave)

    for (int p = 0; p < 31; ++p) {
        const int t0 = 64 + (p << 6);
        if (p > 0) {
#pragma unroll
            for (int l = 0; l < 64; ++l) CPw[l] = CWw[l];
        }
        const ushort_t* cH = &CHb[p & 1][0];
        const ushort_t* cL = &CLb[p & 1][0];
        ushort_t* wH = &CHb[1 - (p & 1)][0];
        ushort_t* wL = &CLb[1 - (p & 1)][0];

        // ---- Lpre = SC0sup @ Cprev^T via split-bf16 MFMA ----
        {
            f32x4 acc[4][4] = {};
            bf16x8 Ah[4][2], Alo[4][2], Bh[4][2], Blo[4][2];
#pragma unroll
            for (int mt = 0; mt < 4; ++mt)
#pragma unroll
                for (int kt = 0; kt < 2; ++kt) {
                    size_t a = ((size_t)b * T_ + t0 + mt * 16 + n16) * 64 + kt * 32 + quad * 8;
                    Ah[mt][kt] = *(const bf16x8*)&S0h[a];
                    Alo[mt][kt] = *(const bf16x8*)&S0l[a];
                }
#pragma unroll
            for (int nt = 0; nt < 4; ++nt)
#pragma unroll
                for (int kt = 0; kt < 2; ++kt) {
                    int a = (nt * 16 + n16) * 72 + kt * 32 + quad * 8;
                    Bh[nt][kt] = *(const bf16x8*)&cH[a];
                    Blo[nt][kt] = *(const bf16x8*)&cL[a];
                }
#pragma unroll
            for (int mt = 0; mt < 4; ++mt)
#pragma unroll
                for (int nt = 0; nt < 4; ++nt)
#pragma unroll
                    for (int kt = 0; kt < 2; ++kt) {
                        acc[mt][nt] = __builtin_amdgcn_mfma_f32_16x16x32_bf16(Ah[mt][kt], Bh[nt][kt], acc[mt][nt], 0, 0, 0);
                        acc[mt][nt] = __builtin_amdgcn_mfma_f32_16x16x32_bf16(Ah[mt][kt], Blo[nt][kt], acc[mt][nt], 0, 0, 0);
                        acc[mt][nt] = __builtin_amdgcn_mfma_f32_16x16x32_bf16(Alo[mt][kt], Bh[nt][kt], acc[mt][nt], 0, 0, 0);
                    }
            // scatter to ULDS[s][l]  (C/D layout: row=quad*4+r, col=lane&15)
#pragma unroll
            for (int mt = 0; mt < 4; ++mt)
#pragma unroll
                for (int nt = 0; nt < 4; ++nt)
#pragma unroll
                    for (int r = 0; r < 4; ++r)
                        ULDS[(mt * 16 + quad * 4 + r) * 67 + nt * 16 + n16] = acc[mt][nt][r];
        }
        // row-distributed logit state: X1[l] = u_{slot l}[t0+lane]
#pragma unroll
        for (int l = 0; l < 64; ++l) X1[l] = ULDS[lane * 67 + l];

        float lgt = ULDS[lane];  // step-0 logits
        float pv = 0.f;

#pragma unroll
        for (int s = 0; s < 64; ++s) {
            float logit = (s > 0 && lane == s - 1) ? pv : lgt;
            // softmax over 64 slots + zero row (no max: logits are O(1))
            float e = __expf(logit);
            float tot = sum64_u(e) + 1.f;  // +exp(0) zero-row
            float alpha = __fdividef(e, tot);
            ALDS[lane] = alpha;
            // prefetch next step's logits (lane s patched via pv)
            if (s < 63) lgt = ULDS[(s + 1) * 67 + lane];
            // u and c updates
            float u0 = 0.f, u1 = 0.f, u2 = 0.f, u3 = 0.f;
            float c0 = 0.f, c1 = 0.f, c2 = 0.f, c3 = 0.f;
            const float4* a4p = (const float4*)ALDS;
#pragma unroll
            for (int i = 0; i < 16; ++i) {
                float4 a4 = a4p[i];
                u0 = fmaf(a4.x, X1[4 * i + 0], u0);
                u1 = fmaf(a4.y, X1[4 * i + 1], u1);
                u2 = fmaf(a4.z, X1[4 * i + 2], u2);
                u3 = fmaf(a4.w, X1[4 * i + 3], u3);
                c0 = fmaf(a4.x, (4 * i + 0 >= s) ? CPw[4 * i + 0] : CWw[4 * i + 0], c0);
                c1 = fmaf(a4.y, (4 * i + 1 >= s) ? CPw[4 * i + 1] : CWw[4 * i + 1], c1);
                c2 = fmaf(a4.z, (4 * i + 2 >= s) ? CPw[4 * i + 2] : CWw[4 * i + 2], c2);
                c3 = fmaf(a4.w, (4 * i + 3 >= s) ? CPw[4 * i + 3] : CWw[4 * i + 3], c3);
            }
            float u_new = (u0 + u1) + (u2 + u3);
            float c_new = (c0 + c1) + (c2 + c3);
            X1[s] = u_new;
            CWw[s] = c_new;
            if (lane > s) ULDS[lane * 67 + s] = u_new;  // future logits of new row s
            if (s < 63) pv = readlane_f(u_new, s + 1);
            gamma[((size_t)b * T_ + t0 + s) * 64 + lane] = c_new;
            ushort_t chh = f32_to_bf16(c_new);
            wH[s * 72 + lane] = chh;
            wL[s * 72 + lane] = f32_to_bf16(c_new - bf16_to_f32(chh));
        }
    }
}

// ---------- K6: prologue rows 0..63: out = LN(tanh(f)*f + f) ----------
__global__ __launch_bounds__(256) void prologue_kernel(
        const float* __restrict__ feat, float* __restrict__ out,
        const float* __restrict__ lng, const float* __restrict__ lnb) {
    int b = blockIdx.y, t = blockIdx.x, tid = threadIdx.x;
    __shared__ float red[4][2];
    size_t base = ((size_t)b * T_ + t) * D_;
    float4 f4 = *(const float4*)&feat[base + tid * 4];
    float4 y;
    y.x = tanh_fast(f4.x) * f4.x + f4.x;
    y.y = tanh_fast(f4.y) * f4.y + f4.y;
    y.z = tanh_fast(f4.z) * f4.z + f4.z;
    y.w = tanh_fast(f4.w) * f4.w + f4.w;
    float s1 = y.x + y.y + y.z + y.w;
    float s2 = y.x * y.x + y.y * y.y + y.z * y.z + y.w * y.w;
#pragma unroll
    for (int m = 1; m < 64; m <<= 1) { s1 += __shfl_xor(s1, m, 64); s2 += __shfl_xor(s2, m, 64); }
    if ((tid & 63) == 0) { red[tid >> 6][0] = s1; red[tid >> 6][1] = s2; }
    __syncthreads();
    float mu = (red[0][0] + red[1][0] + red[2][0] + red[3][0]) * (1.f / D_);
    float m2 = (red[0][1] + red[1][1] + red[2][1] + red[3][1]) * (1.f / D_);
    float rv = rsqrtf(fmaxf(m2 - mu * mu, 0.f) + LN_EPS);
    float4 g4 = *(const float4*)&lng[tid * 4];
    float4 b4 = *(const float4*)&lnb[tid * 4];
    float4 o;
    o.x = (y.x - mu) * rv * g4.x + b4.x;
    o.y = (y.y - mu) * rv * g4.y + b4.y;
    o.z = (y.z - mu) * rv * g4.z + b4.z;
    o.w = (y.w - mu) * rv * g4.w + b4.w;
    *(float4*)&out[base + tid * 4] = o;
}

// ---------- K7: V = Γ @ F0 (split-bf16 MFMA) fused with gate + LayerNorm ----------
__global__ __launch_bounds__(256) void final_kernel(
        const float* __restrict__ gamma, const ushort_t* __restrict__ fTh,
        const ushort_t* __restrict__ fTl, const float* __restrict__ feat,
        const float* __restrict__ lng, const float* __restrict__ lnb,
        float* __restrict__ out) {
    const int b = blockIdx.y;
    const int t0 = 64 + blockIdx.x * 16;
    const int tid = threadIdx.x, lane = tid & 63, wv = tid >> 6;
    const int n16 = lane & 15, quad = lane >> 4;
    __shared__ float wsum[4][16][2];
    __shared__ float lnp[16][2];

    bf16x8 Ah[2], Alo[2];
    {
        const float* gr = &gamma[((size_t)b * T_ + t0 + n16) * 64];
#pragma unroll
        for (int kt = 0; kt < 2; ++kt) {
            float g[8];
            *(float4*)&g[0] = *(const float4*)&gr[kt * 32 + quad * 8];
            *(float4*)&g[4] = *(const float4*)&gr[kt * 32 + quad * 8 + 4];
            bf16x8 h, l;
#pragma unroll
            for (int i = 0; i < 8; ++i) {
                ushort_t hh = f32_to_bf16(g[i]);
                h[i] = (short)hh;
                l[i] = (short)f32_to_bf16(g[i] - bf16_to_f32(hh));
            }
            Ah[kt] = h; Alo[kt] = l;
        }
    }
    f32x4 acc[16];
#pragma unroll
    for (int j = 0; j < 16; ++j) {
        const int d = wv * 256 + j * 16 + n16;
        const ushort_t* fr = &fTh[((size_t)b * D_ + d) * 64];
        const ushort_t* fr2 = &fTl[((size_t)b * D_ + d) * 64];
        f32x4 a = {0.f, 0.f, 0.f, 0.f};
#pragma unroll
        for (int kt = 0; kt < 2; ++kt) {
            bf16x8 bh = *(const bf16x8*)&fr[kt * 32 + quad * 8];
            bf16x8 bl = *(const bf16x8*)&fr2[kt * 32 + quad * 8];
            a = __builtin_amdgcn_mfma_f32_16x16x32_bf16(Ah[kt], bh, a, 0, 0, 0);
            a = __builtin_amdgcn_mfma_f32_16x16x32_bf16(Ah[kt], bl, a, 0, 0, 0);
            a = __builtin_amdgcn_mfma_f32_16x16x32_bf16(Alo[kt], bh, a, 0, 0, 0);
        }
        acc[j] = a;
    }
    // gate + accumulate LN stats; rows m = quad*4+r
    float s1[4] = {0.f, 0.f, 0.f, 0.f}, s2[4] = {0.f, 0.f, 0.f, 0.f};
#pragma unroll
    for (int j = 0; j < 16; ++j) {
        const int d = wv * 256 + j * 16 + n16;
#pragma unroll
        for (int r = 0; r < 4; ++r) {
            float f = feat[((size_t)b * T_ + t0 + quad * 4 + r) * D_ + d];
            float y = tanh_fast(acc[j][r]) * f + f;
            acc[j][r] = y;
            s1[r] += y;
            s2[r] += y * y;
        }
    }
#pragma unroll
    for (int m = 1; m < 16; m <<= 1)
#pragma unroll
        for (int r = 0; r < 4; ++r) { s1[r] += __shfl_xor(s1[r], m, 64); s2[r] += __shfl_xor(s2[r], m, 64); }
    if (n16 == 0) {
#pragma unroll
        for (int r = 0; r < 4; ++r) { wsum[wv][quad * 4 + r][0] = s1[r]; wsum[wv][quad * 4 + r][1] = s2[r]; }
    }
    __syncthreads();
    if (tid < 16) {
        float a = 0.f, c = 0.f;
#pragma unroll
        for (int w2 = 0; w2 < 4; ++w2) { a += wsum[w2][tid][0]; c += wsum[w2][tid][1]; }
        float mu = a * (1.f / D_);
        float var = c * (1.f / D_) - mu * mu;
        lnp[tid][0] = mu;
        lnp[tid][1] = rsqrtf(fmaxf(var, 0.f) + LN_EPS);
    }
    __syncthreads();
#pragma unroll
    for (int j = 0; j < 16; ++j) {
        const int d = wv * 256 + j * 16 + n16;
        float gd = lng[d], bd = lnb[d];
#pragma unroll
        for (int r = 0; r < 4; ++r) {
            int row = quad * 4 + r;
            out[((size_t)b * T_ + t0 + row) * D_ + d] = (acc[j][r] - lnp[row][0]) * lnp[row][1] * gd + bd;
        }
    }
}

extern "C" void kernel_launch(void* const* d_in, const int* in_sizes, int n_in,
                              void* d_out, int out_size, void* d_ws, size_t ws_size,
                              hipStream_t stream) {
    const float* feature = (const float*)d_in[0];
    const float* wq_w    = (const float*)d_in[1];
    const float* wq_b    = (const float*)d_in[2];
    const float* w2_w    = (const float*)d_in[3];
    // d_in[4] = w2_b: softmax-invariant, unused
    const float* ln_g    = (const float*)d_in[5];
    const float* ln_b    = (const float*)d_in[6];
    float* out = (float*)d_out;

    uint8_t* ws = (uint8_t*)d_ws;
    // phase-1 regions
    ushort_t* featbf = (ushort_t*)(ws);                       // 32 MB (dead after gemm_qw)
    ushort_t* wqT    = (ushort_t*)(ws + 32u * 1024 * 1024);   // 2 MB
    // phase-2 regions (alias featbf space)
    float*    gamma = (float*)(ws);                           // 4 MB
    ushort_t* S0h   = (ushort_t*)(ws + 4u * 1024 * 1024);     // 2 MB
    ushort_t* S0l   = (ushort_t*)(ws + 6u * 1024 * 1024);     // 2 MB
    float*    fT32  = (float*)(ws + 8u * 1024 * 1024);        // 2 MB
    ushort_t* fTh   = (ushort_t*)(ws + 10u * 1024 * 1024);    // 1 MB
    ushort_t* fTl   = (ushort_t*)(ws + 11u * 1024 * 1024);    // 1 MB

    const int ntot = B_ * T_ * D_;
    cvt_feat<<<(ntot + 255) / 256, 256, 0, stream>>>(feature, featbf, ntot);
    cvt_wqT<<<dim3(16, 16), 256, 0, stream>>>(wq_w, wqT);
    gemm_qw<<<dim3(128, 16), 256, 0, stream>>>(featbf, wqT, wq_b, w2_w, out);
    featT_kernel<<<dim3(16, 8), 256, 0, stream>>>(feature, fT32, fTh, fTl);
    s0_gemm<<<dim3(31, 8), 256, 0, stream>>>(out, fT32, S0h, S0l);
    core_kernel<<<8, 64, 0, stream>>>(S0h, S0l, gamma);
    prologue_kernel<<<dim3(64, 8), 256, 0, stream>>>(feature, out, ln_g, ln_b);
    final_kernel<<<dim3(124, 8), 256, 0, stream>>>(gamma, fTh, fTl, feature, ln_g, ln_b, out);
}

// Round 4
// 2707.812 us; speedup vs baseline: 4.1009x; 1.0344x over previous
//
#include <hip/hip_runtime.h>
#include <hip/hip_bf16.h>

#define B_ 8
#define T_ 2048
#define D_ 1024
#define W_ 64
#define LN_EPS 1e-5f

typedef __attribute__((ext_vector_type(8))) short bf16x8;
typedef __attribute__((ext_vector_type(4))) float f32x4;
typedef unsigned short ushort_t;

__device__ __forceinline__ ushort_t f32_to_bf16(float f) {
    union { float ff; unsigned u; } c; c.ff = f;
    unsigned r = (c.u + 0x7fffu + ((c.u >> 16) & 1u)) >> 16;
    return (ushort_t)r;
}
__device__ __forceinline__ float bf16_to_f32(ushort_t h) {
    union { unsigned u; float f; } c; c.u = ((unsigned)h) << 16; return c.f;
}
__device__ __forceinline__ float tanh_fast(float x) {
    float xx = fminf(fmaxf(x, -20.f), 20.f);
    float e = __expf(2.f * xx);
    return 1.f - 2.f / (e + 1.f);
}
__device__ __forceinline__ float readlane_f(float v, int l) {
    return __int_as_float(__builtin_amdgcn_readlane(__float_as_int(v), l));
}
// DPP-based add with immediate control (template => constant integer)
template <int CTRL>
__device__ __forceinline__ float dpp_add(float x) {
    int y = __builtin_amdgcn_update_dpp(0, __float_as_int(x), CTRL, 0xf, 0xf, true);
    return x + __int_as_float(y);
}
__device__ __forceinline__ float sum64_dpp(float x) {
    x = dpp_add<0x111>(x);  // row_shr:1
    x = dpp_add<0x112>(x);  // row_shr:2
    x = dpp_add<0x114>(x);  // row_shr:4
    x = dpp_add<0x118>(x);  // row_shr:8  -> lane15/31/47/63 hold row16 sums
    x = dpp_add<0x142>(x);  // row_bcast:15 -> lane31 = rows0+1, lane63 = rows2+3
    x = dpp_add<0x143>(x);  // row_bcast:31 -> lane63 = total
    return readlane_f(x, 63);
}

// ---------- K0: feature -> bf16 ----------
__global__ void cvt_feat(const float* __restrict__ f, ushort_t* __restrict__ o, int n) {
    int i = blockIdx.x * blockDim.x + threadIdx.x;
    if (i < n) o[i] = f32_to_bf16(f[i]);
}

// ---------- K1: wqT[n][k] = bf16(wq[k][n]) ----------
__global__ void cvt_wqT(const float* __restrict__ wq, ushort_t* __restrict__ o) {
    __shared__ float tile[64][65];
    int bi = blockIdx.x, bj = blockIdx.y, tid = threadIdx.x;
    int c = tid & 63, r4 = tid >> 6;
    for (int it = 0; it < 16; ++it) {
        int r = it * 4 + r4;
        tile[r][c] = wq[(size_t)(bi * 64 + r) * D_ + bj * 64 + c];
    }
    __syncthreads();
    for (int it = 0; it < 16; ++it) {
        int r = it * 4 + r4;
        o[(size_t)(bj * 64 + r) * D_ + bi * 64 + c] = f32_to_bf16(tile[c][r]);
    }
}

// ---------- K2: qw = (featbf @ wqT^T + wq_b) * w2_w  (MFMA bf16) ----------
__global__ __launch_bounds__(256) void gemm_qw(
        const ushort_t* __restrict__ A, const ushort_t* __restrict__ BT,
        const float* __restrict__ wqb, const float* __restrict__ w2w,
        float* __restrict__ out) {
    const int K = 1024;
    __shared__ ushort_t Al[128][48];
    __shared__ ushort_t Bl[64][48];
    int tid = threadIdx.x;
    int lane = tid & 63, wv = tid >> 6;
    int wm = wv >> 1, wn = wv & 1;
    int m0 = blockIdx.x * 128, n0 = blockIdx.y * 64;
    int mrow = lane & 15, quad = lane >> 4;
    f32x4 acc[4][2] = {};
    for (int k0 = 0; k0 < K; k0 += 32) {
#pragma unroll
        for (int rep = 0; rep < 2; ++rep) {
            int idx = rep * 256 + tid;
            int r = idx >> 2, cp = (idx & 3) * 8;
            *(bf16x8*)&Al[r][cp] = *(const bf16x8*)&A[(size_t)(m0 + r) * K + k0 + cp];
        }
        {
            int r = tid >> 2, cp = (tid & 3) * 8;
            *(bf16x8*)&Bl[r][cp] = *(const bf16x8*)&BT[(size_t)(n0 + r) * K + k0 + cp];
        }
        __syncthreads();
        bf16x8 af[4], bfr[2];
#pragma unroll
        for (int ms = 0; ms < 4; ++ms) af[ms] = *(bf16x8*)&Al[wm * 64 + ms * 16 + mrow][quad * 8];
#pragma unroll
        for (int ns = 0; ns < 2; ++ns) bfr[ns] = *(bf16x8*)&Bl[wn * 32 + ns * 16 + mrow][quad * 8];
#pragma unroll
        for (int ms = 0; ms < 4; ++ms)
#pragma unroll
            for (int ns = 0; ns < 2; ++ns)
                acc[ms][ns] = __builtin_amdgcn_mfma_f32_16x16x32_bf16(af[ms], bfr[ns], acc[ms][ns], 0, 0, 0);
        __syncthreads();
    }
#pragma unroll
    for (int ns = 0; ns < 2; ++ns) {
        int n = n0 + wn * 32 + ns * 16 + mrow;
        float scale = w2w[n], bias = wqb[n];
#pragma unroll
        for (int ms = 0; ms < 4; ++ms) {
#pragma unroll
            for (int r = 0; r < 4; ++r) {
                int m = m0 + wm * 64 + ms * 16 + quad * 4 + r;
                out[(size_t)m * D_ + n] = (acc[ms][ns][r] + bias) * scale;
            }
        }
    }
}

// ---------- K3: transpose first 64 feature rows: fT32/fTh/fTl [b][d][w] ----------
__global__ void featT_kernel(const float* __restrict__ feat, float* __restrict__ fT32,
                             ushort_t* __restrict__ fTh, ushort_t* __restrict__ fTl) {
    __shared__ float tile[64][65];
    int d0 = blockIdx.x * 64, b = blockIdx.y, tid = threadIdx.x;
    int c = tid & 63, r4 = tid >> 6;
#pragma unroll
    for (int it = 0; it < 16; ++it) {
        int r = it * 4 + r4;  // window row w
        tile[r][c] = feat[((size_t)b * T_ + r) * D_ + d0 + c];
    }
    __syncthreads();
#pragma unroll
    for (int it = 0; it < 16; ++it) {
        int r = it * 4 + r4;  // d offset
        float v = tile[c][r]; // = feature[b][w=c][d0+r]
        size_t o = ((size_t)b * D_ + d0 + r) * 64 + c;
        fT32[o] = v;
        ushort_t h = f32_to_bf16(v);
        fTh[o] = h;
        fTl[o] = f32_to_bf16(v - bf16_to_f32(h));
    }
}

// ---------- K4: S0[b][t][w] = qw[b][t]·F0[b][w]  (fp32, stored as bf16 hi/lo) ----------
__global__ __launch_bounds__(256) void s0_gemm(
        const float* __restrict__ qw, const float* __restrict__ fT32,
        ushort_t* __restrict__ S0h, ushort_t* __restrict__ S0l) {
    __shared__ float As[64][17];
    __shared__ float Bs[16][65];
    int b = blockIdx.y;
    int t0 = 64 + blockIdx.x * 64;
    int tx = threadIdx.x & 15, ty = threadIdx.x >> 4;
    float acc[4][4] = {};
    for (int k0 = 0; k0 < D_; k0 += 16) {
#pragma unroll
        for (int i = 0; i < 4; ++i) {
            int idx = i * 256 + threadIdx.x;
            int r = idx >> 4, c = idx & 15;
            As[r][c] = qw[((size_t)b * T_ + t0 + r) * D_ + k0 + c];
        }
#pragma unroll
        for (int i = 0; i < 4; ++i) {
            int idx = i * 256 + threadIdx.x;
            int r = idx >> 6, c = idx & 63;
            Bs[r][c] = fT32[((size_t)b * D_ + k0 + r) * 64 + c];
        }
        __syncthreads();
#pragma unroll
        for (int kk = 0; kk < 16; ++kk)
#pragma unroll
            for (int i = 0; i < 4; ++i)
#pragma unroll
                for (int j = 0; j < 4; ++j)
                    acc[i][j] = fmaf(As[ty * 4 + i][kk], Bs[kk][tx * 4 + j], acc[i][j]);
        __syncthreads();
    }
#pragma unroll
    for (int i = 0; i < 4; ++i)
#pragma unroll
        for (int j = 0; j < 4; ++j) {
            float sc = acc[i][j];
            ushort_t h = f32_to_bf16(sc);
            size_t o = ((size_t)b * T_ + t0 + ty * 4 + i) * 64 + tx * 4 + j;
            S0h[o] = h;
            S0l[o] = f32_to_bf16(sc - bf16_to_f32(h));
        }
}

// ---------- K5: sequential core, 1 wave per batch, register-resident state ----------
// State per lane: X1[64] (u-values, lane = time position) + C[64] (basis coeffs,
// lane = F0-basis index). Both updated IN PLACE: at step s, slot l holds the
// previous-generation row for l >= s and the new row for l < s — exactly the
// read-before-overwrite semantics of a single array. 128 state VGPRs -> no spill.
__global__ __launch_bounds__(64) void core_kernel(
        const ushort_t* __restrict__ S0h, const ushort_t* __restrict__ S0l,
        float* __restrict__ gamma) {
    const int b = blockIdx.x;
    const int lane = threadIdx.x;
    const int n16 = lane & 15, quad = lane >> 4;
    __shared__ float ULDS[64 * 67];
    __shared__ __align__(16) float ALDS[64];
    __shared__ ushort_t CH[64 * 72];
    __shared__ ushort_t CL[64 * 72];

    float C[64];
#pragma unroll
    for (int l = 0; l < 64; ++l) C[l] = (l == lane) ? 1.f : 0.f;
#pragma unroll
    for (int j = 0; j < 72; ++j) {
        CH[lane * 72 + j] = (j == lane) ? (ushort_t)0x3F80 : (ushort_t)0;
        CL[lane * 72 + j] = 0;
    }
    // single wave: DS pipe is in-order per wave; no barriers needed.

#pragma unroll 1
    for (int p = 0; p < 31; ++p) {
        const int t0 = 64 + (p << 6);

        // ---- Lpre = S0sup @ C^T via split-bf16 MFMA (per-mt tiles to cap VGPRs) ----
        {
            bf16x8 Bh[4][2], Blo[4][2];
#pragma unroll
            for (int nt = 0; nt < 4; ++nt)
#pragma unroll
                for (int kt = 0; kt < 2; ++kt) {
                    int a = (nt * 16 + n16) * 72 + kt * 32 + quad * 8;
                    Bh[nt][kt] = *(const bf16x8*)&CH[a];
                    Blo[nt][kt] = *(const bf16x8*)&CL[a];
                }
#pragma unroll
            for (int mt = 0; mt < 4; ++mt) {
                bf16x8 Ah[2], Alo2[2];
#pragma unroll
                for (int kt = 0; kt < 2; ++kt) {
                    size_t a = ((size_t)b * T_ + t0 + mt * 16 + n16) * 64 + kt * 32 + quad * 8;
                    Ah[kt] = *(const bf16x8*)&S0h[a];
                    Alo2[kt] = *(const bf16x8*)&S0l[a];
                }
                f32x4 acc[4] = {};
#pragma unroll
                for (int nt = 0; nt < 4; ++nt)
#pragma unroll
                    for (int kt = 0; kt < 2; ++kt) {
                        acc[nt] = __builtin_amdgcn_mfma_f32_16x16x32_bf16(Ah[kt], Bh[nt][kt], acc[nt], 0, 0, 0);
                        acc[nt] = __builtin_amdgcn_mfma_f32_16x16x32_bf16(Ah[kt], Blo[nt][kt], acc[nt], 0, 0, 0);
                        acc[nt] = __builtin_amdgcn_mfma_f32_16x16x32_bf16(Alo2[kt], Bh[nt][kt], acc[nt], 0, 0, 0);
                    }
                // C/D layout: row = quad*4+r, col = n16
#pragma unroll
                for (int nt = 0; nt < 4; ++nt)
#pragma unroll
                    for (int r = 0; r < 4; ++r)
                        ULDS[(mt * 16 + quad * 4 + r) * 67 + nt * 16 + n16] = acc[nt][r];
            }
        }

        // X1[l] = u of slot l at time position (t0+lane)
        float X1[64];
#pragma unroll
        for (int l = 0; l < 64; ++l) X1[l] = ULDS[lane * 67 + l];

        float lgt = ULDS[lane];  // step-0 logits (position 0, slot lane)
        float pv = 0.f;

#pragma unroll
        for (int s = 0; s < 64; ++s) {
            float logit = (s > 0 && lane == s - 1) ? pv : lgt;
            // softmax over 64 slots + zero row (logits are O(1): no max subtraction)
            float e = __expf(logit);
            float tot = sum64_dpp(e) + 1.f;  // + exp(0) zero-row
            float alpha = __fdividef(e, tot);
            ALDS[lane] = alpha;
            if (s < 63) lgt = ULDS[(s + 1) * 67 + lane];
            // u and c updates (in-place window semantics)
            float u0 = 0.f, u1 = 0.f, u2 = 0.f, u3 = 0.f;
            float c0 = 0.f, c1 = 0.f, c2 = 0.f, c3 = 0.f;
            const float4* a4p = (const float4*)ALDS;
#pragma unroll
            for (int i = 0; i < 16; ++i) {
                float4 a4 = a4p[i];
                u0 = fmaf(a4.x, X1[4 * i + 0], u0);
                u1 = fmaf(a4.y, X1[4 * i + 1], u1);
                u2 = fmaf(a4.z, X1[4 * i + 2], u2);
                u3 = fmaf(a4.w, X1[4 * i + 3], u3);
                c0 = fmaf(a4.x, C[4 * i + 0], c0);
                c1 = fmaf(a4.y, C[4 * i + 1], c1);
                c2 = fmaf(a4.z, C[4 * i + 2], c2);
                c3 = fmaf(a4.w, C[4 * i + 3], c3);
            }
            float u_new = (u0 + u1) + (u2 + u3);
            float c_new = (c0 + c1) + (c2 + c3);
            X1[s] = u_new;
            C[s] = c_new;
            if (lane > s) ULDS[lane * 67 + s] = u_new;  // future logits of new row s
            if (s < 63) pv = readlane_f(u_new, s + 1);
            gamma[((size_t)b * T_ + t0 + s) * 64 + lane] = c_new;
            ushort_t chh = f32_to_bf16(c_new);
            CH[s * 72 + lane] = chh;
            CL[s * 72 + lane] = f32_to_bf16(c_new - bf16_to_f32(chh));
        }
    }
}

// ---------- K6: prologue rows 0..63: out = LN(tanh(f)*f + f) ----------
__global__ __launch_bounds__(256) void prologue_kernel(
        const float* __restrict__ feat, float* __restrict__ out,
        const float* __restrict__ lng, const float* __restrict__ lnb) {
    int b = blockIdx.y, t = blockIdx.x, tid = threadIdx.x;
    __shared__ float red[4][2];
    size_t base = ((size_t)b * T_ + t) * D_;
    float4 f4 = *(const float4*)&feat[base + tid * 4];
    float4 y;
    y.x = tanh_fast(f4.x) * f4.x + f4.x;
    y.y = tanh_fast(f4.y) * f4.y + f4.y;
    y.z = tanh_fast(f4.z) * f4.z + f4.z;
    y.w = tanh_fast(f4.w) * f4.w + f4.w;
    float s1 = y.x + y.y + y.z + y.w;
    float s2 = y.x * y.x + y.y * y.y + y.z * y.z + y.w * y.w;
#pragma unroll
    for (int m = 1; m < 64; m <<= 1) { s1 += __shfl_xor(s1, m, 64); s2 += __shfl_xor(s2, m, 64); }
    if ((tid & 63) == 0) { red[tid >> 6][0] = s1; red[tid >> 6][1] = s2; }
    __syncthreads();
    float mu = (red[0][0] + red[1][0] + red[2][0] + red[3][0]) * (1.f / D_);
    float m2 = (red[0][1] + red[1][1] + red[2][1] + red[3][1]) * (1.f / D_);
    float rv = rsqrtf(fmaxf(m2 - mu * mu, 0.f) + LN_EPS);
    float4 g4 = *(const float4*)&lng[tid * 4];
    float4 b4 = *(const float4*)&lnb[tid * 4];
    float4 o;
    o.x = (y.x - mu) * rv * g4.x + b4.x;
    o.y = (y.y - mu) * rv * g4.y + b4.y;
    o.z = (y.z - mu) * rv * g4.z + b4.z;
    o.w = (y.w - mu) * rv * g4.w + b4.w;
    *(float4*)&out[base + tid * 4] = o;
}

// ---------- K7: V = Γ @ F0 (split-bf16 MFMA) fused with gate + LayerNorm ----------
__global__ __launch_bounds__(256) void final_kernel(
        const float* __restrict__ gamma, const ushort_t* __restrict__ fTh,
        const ushort_t* __restrict__ fTl, const float* __restrict__ feat,
        const float* __restrict__ lng, const float* __restrict__ lnb,
        float* __restrict__ out) {
    const int b = blockIdx.y;
    const int t0 = 64 + blockIdx.x * 16;
    const int tid = threadIdx.x, lane = tid & 63, wv = tid >> 6;
    const int n16 = lane & 15, quad = lane >> 4;
    __shared__ float wsum[4][16][2];
    __shared__ float lnp[16][2];

    bf16x8 Ah[2], Alo[2];
    {
        const float* gr = &gamma[((size_t)b * T_ + t0 + n16) * 64];
#pragma unroll
        for (int kt = 0; kt < 2; ++kt) {
            float g[8];
            *(float4*)&g[0] = *(const float4*)&gr[kt * 32 + quad * 8];
            *(float4*)&g[4] = *(const float4*)&gr[kt * 32 + quad * 8 + 4];
            bf16x8 h, l;
#pragma unroll
            for (int i = 0; i < 8; ++i) {
                ushort_t hh = f32_to_bf16(g[i]);
                h[i] = (short)hh;
                l[i] = (short)f32_to_bf16(g[i] - bf16_to_f32(hh));
            }
            Ah[kt] = h; Alo[kt] = l;
        }
    }
    f32x4 acc[16];
#pragma unroll
    for (int j = 0; j < 16; ++j) {
        const int d = wv * 256 + j * 16 + n16;
        const ushort_t* fr = &fTh[((size_t)b * D_ + d) * 64];
        const ushort_t* fr2 = &fTl[((size_t)b * D_ + d) * 64];
        f32x4 a = {0.f, 0.f, 0.f, 0.f};
#pragma unroll
        for (int kt = 0; kt < 2; ++kt) {
            bf16x8 bh = *(const bf16x8*)&fr[kt * 32 + quad * 8];
            bf16x8 bl = *(const bf16x8*)&fr2[kt * 32 + quad * 8];
            a = __builtin_amdgcn_mfma_f32_16x16x32_bf16(Ah[kt], bh, a, 0, 0, 0);
            a = __builtin_amdgcn_mfma_f32_16x16x32_bf16(Ah[kt], bl, a, 0, 0, 0);
            a = __builtin_amdgcn_mfma_f32_16x16x32_bf16(Alo[kt], bh, a, 0, 0, 0);
        }
        acc[j] = a;
    }
    float s1[4] = {0.f, 0.f, 0.f, 0.f}, s2[4] = {0.f, 0.f, 0.f, 0.f};
#pragma unroll
    for (int j = 0; j < 16; ++j) {
        const int d = wv * 256 + j * 16 + n16;
#pragma unroll
        for (int r = 0; r < 4; ++r) {
            float f = feat[((size_t)b * T_ + t0 + quad * 4 + r) * D_ + d];
            float y = tanh_fast(acc[j][r]) * f + f;
            acc[j][r] = y;
            s1[r] += y;
            s2[r] += y * y;
        }
    }
#pragma unroll
    for (int m = 1; m < 16; m <<= 1)
#pragma unroll
        for (int r = 0; r < 4; ++r) { s1[r] += __shfl_xor(s1[r], m, 64); s2[r] += __shfl_xor(s2[r], m, 64); }
    if (n16 == 0) {
#pragma unroll
        for (int r = 0; r < 4; ++r) { wsum[wv][quad * 4 + r][0] = s1[r]; wsum[wv][quad * 4 + r][1] = s2[r]; }
    }
    __syncthreads();
    if (tid < 16) {
        float a = 0.f, c = 0.f;
#pragma unroll
        for (int w2 = 0; w2 < 4; ++w2) { a += wsum[w2][tid][0]; c += wsum[w2][tid][1]; }
        float mu = a * (1.f / D_);
        float var = c * (1.f / D_) - mu * mu;
        lnp[tid][0] = mu;
        lnp[tid][1] = rsqrtf(fmaxf(var, 0.f) + LN_EPS);
    }
    __syncthreads();
#pragma unroll
    for (int j = 0; j < 16; ++j) {
        const int d = wv * 256 + j * 16 + n16;
        float gd = lng[d], bd = lnb[d];
#pragma unroll
        for (int r = 0; r < 4; ++r) {
            int row = quad * 4 + r;
            out[((size_t)b * T_ + t0 + row) * D_ + d] = (acc[j][r] - lnp[row][0]) * lnp[row][1] * gd + bd;
        }
    }
}

extern "C" void kernel_launch(void* const* d_in, const int* in_sizes, int n_in,
                              void* d_out, int out_size, void* d_ws, size_t ws_size,
                              hipStream_t stream) {
    const float* feature = (const float*)d_in[0];
    const float* wq_w    = (const float*)d_in[1];
    const float* wq_b    = (const float*)d_in[2];
    const float* w2_w    = (const float*)d_in[3];
    // d_in[4] = w2_b: softmax-invariant, unused
    const float* ln_g    = (const float*)d_in[5];
    const float* ln_b    = (const float*)d_in[6];
    float* out = (float*)d_out;

    uint8_t* ws = (uint8_t*)d_ws;
    // phase-1 regions
    ushort_t* featbf = (ushort_t*)(ws);                       // 32 MB (dead after gemm_qw)
    ushort_t* wqT    = (ushort_t*)(ws + 32u * 1024 * 1024);   // 2 MB
    // phase-2 regions (alias featbf space)
    float*    gamma = (float*)(ws);                           // 4 MB
    ushort_t* S0h   = (ushort_t*)(ws + 4u * 1024 * 1024);     // 2 MB
    ushort_t* S0l   = (ushort_t*)(ws + 6u * 1024 * 1024);     // 2 MB
    float*    fT32  = (float*)(ws + 8u * 1024 * 1024);        // 2 MB
    ushort_t* fTh   = (ushort_t*)(ws + 10u * 1024 * 1024);    // 1 MB
    ushort_t* fTl   = (ushort_t*)(ws + 11u * 1024 * 1024);    // 1 MB

    const int ntot = B_ * T_ * D_;
    cvt_feat<<<(ntot + 255) / 256, 256, 0, stream>>>(feature, featbf, ntot);
    cvt_wqT<<<dim3(16, 16), 256, 0, stream>>>(wq_w, wqT);
    gemm_qw<<<dim3(128, 16), 256, 0, stream>>>(featbf, wqT, wq_b, w2_w, out);
    featT_kernel<<<dim3(16, 8), 256, 0, stream>>>(feature, fT32, fTh, fTl);
    s0_gemm<<<dim3(31, 8), 256, 0, stream>>>(out, fT32, S0h, S0l);
    core_kernel<<<8, 64, 0, stream>>>(S0h, S0l, gamma);
    prologue_kernel<<<dim3(64, 8), 256, 0, stream>>>(feature, out, ln_g, ln_b);
    final_kernel<<<dim3(124, 8), 256, 0, stream>>>(gamma, fTh, fTl, feature, ln_g, ln_b, out);
}

// Round 5
// 1458.667 us; speedup vs baseline: 7.6127x; 1.8564x over previous
//
#include <hip/hip_runtime.h>
#include <hip/hip_bf16.h>

#define B_ 8
#define T_ 2048
#define D_ 1024
#define W_ 64
#define LN_EPS 1e-5f

typedef __attribute__((ext_vector_type(8))) short bf16x8;
typedef __attribute__((ext_vector_type(4))) float f32x4;
typedef unsigned short ushort_t;

__device__ __forceinline__ ushort_t f32_to_bf16(float f) {
    union { float ff; unsigned u; } c; c.ff = f;
    unsigned r = (c.u + 0x7fffu + ((c.u >> 16) & 1u)) >> 16;
    return (ushort_t)r;
}
__device__ __forceinline__ float bf16_to_f32(ushort_t h) {
    union { unsigned u; float f; } c; c.u = ((unsigned)h) << 16; return c.f;
}
__device__ __forceinline__ float tanh_fast(float x) {
    float xx = fminf(fmaxf(x, -20.f), 20.f);
    float e = __expf(2.f * xx);
    return 1.f - 2.f / (e + 1.f);
}
__device__ __forceinline__ float readlane_f(float v, int l) {
    return __int_as_float(__builtin_amdgcn_readlane(__float_as_int(v), l));
}
// DPP-based add with immediate control (template => constant integer)
template <int CTRL>
__device__ __forceinline__ float dpp_add(float x) {
    int y = __builtin_amdgcn_update_dpp(0, __float_as_int(x), CTRL, 0xf, 0xf, true);
    return x + __int_as_float(y);
}
__device__ __forceinline__ float sum64_dpp(float x) {
    x = dpp_add<0x111>(x);  // row_shr:1
    x = dpp_add<0x112>(x);  // row_shr:2
    x = dpp_add<0x114>(x);  // row_shr:4
    x = dpp_add<0x118>(x);  // row_shr:8
    x = dpp_add<0x142>(x);  // row_bcast:15
    x = dpp_add<0x143>(x);  // row_bcast:31 -> lane63 = total
    return readlane_f(x, 63);
}

// ---------- K0: feature -> bf16 ----------
__global__ void cvt_feat(const float* __restrict__ f, ushort_t* __restrict__ o, int n) {
    int i = blockIdx.x * blockDim.x + threadIdx.x;
    if (i < n) o[i] = f32_to_bf16(f[i]);
}

// ---------- K1: wqT[n][k] = bf16(wq[k][n]) ----------
__global__ void cvt_wqT(const float* __restrict__ wq, ushort_t* __restrict__ o) {
    __shared__ float tile[64][65];
    int bi = blockIdx.x, bj = blockIdx.y, tid = threadIdx.x;
    int c = tid & 63, r4 = tid >> 6;
    for (int it = 0; it < 16; ++it) {
        int r = it * 4 + r4;
        tile[r][c] = wq[(size_t)(bi * 64 + r) * D_ + bj * 64 + c];
    }
    __syncthreads();
    for (int it = 0; it < 16; ++it) {
        int r = it * 4 + r4;
        o[(size_t)(bj * 64 + r) * D_ + bi * 64 + c] = f32_to_bf16(tile[c][r]);
    }
}

// ---------- K2: qw = (featbf @ wqT^T + wq_b) * w2_w  (MFMA bf16) ----------
__global__ __launch_bounds__(256) void gemm_qw(
        const ushort_t* __restrict__ A, const ushort_t* __restrict__ BT,
        const float* __restrict__ wqb, const float* __restrict__ w2w,
        float* __restrict__ out) {
    const int K = 1024;
    __shared__ ushort_t Al[128][48];
    __shared__ ushort_t Bl[64][48];
    int tid = threadIdx.x;
    int lane = tid & 63, wv = tid >> 6;
    int wm = wv >> 1, wn = wv & 1;
    int m0 = blockIdx.x * 128, n0 = blockIdx.y * 64;
    int mrow = lane & 15, quad = lane >> 4;
    f32x4 acc[4][2] = {};
    for (int k0 = 0; k0 < K; k0 += 32) {
#pragma unroll
        for (int rep = 0; rep < 2; ++rep) {
            int idx = rep * 256 + tid;
            int r = idx >> 2, cp = (idx & 3) * 8;
            *(bf16x8*)&Al[r][cp] = *(const bf16x8*)&A[(size_t)(m0 + r) * K + k0 + cp];
        }
        {
            int r = tid >> 2, cp = (tid & 3) * 8;
            *(bf16x8*)&Bl[r][cp] = *(const bf16x8*)&BT[(size_t)(n0 + r) * K + k0 + cp];
        }
        __syncthreads();
        bf16x8 af[4], bfr[2];
#pragma unroll
        for (int ms = 0; ms < 4; ++ms) af[ms] = *(bf16x8*)&Al[wm * 64 + ms * 16 + mrow][quad * 8];
#pragma unroll
        for (int ns = 0; ns < 2; ++ns) bfr[ns] = *(bf16x8*)&Bl[wn * 32 + ns * 16 + mrow][quad * 8];
#pragma unroll
        for (int ms = 0; ms < 4; ++ms)
#pragma unroll
            for (int ns = 0; ns < 2; ++ns)
                acc[ms][ns] = __builtin_amdgcn_mfma_f32_16x16x32_bf16(af[ms], bfr[ns], acc[ms][ns], 0, 0, 0);
        __syncthreads();
    }
#pragma unroll
    for (int ns = 0; ns < 2; ++ns) {
        int n = n0 + wn * 32 + ns * 16 + mrow;
        float scale = w2w[n], bias = wqb[n];
#pragma unroll
        for (int ms = 0; ms < 4; ++ms) {
#pragma unroll
            for (int r = 0; r < 4; ++r) {
                int m = m0 + wm * 64 + ms * 16 + quad * 4 + r;
                out[(size_t)m * D_ + n] = (acc[ms][ns][r] + bias) * scale;
            }
        }
    }
}

// ---------- K3: transpose first 64 feature rows: fT32/fTh/fTl [b][d][w] ----------
__global__ void featT_kernel(const float* __restrict__ feat, float* __restrict__ fT32,
                             ushort_t* __restrict__ fTh, ushort_t* __restrict__ fTl) {
    __shared__ float tile[64][65];
    int d0 = blockIdx.x * 64, b = blockIdx.y, tid = threadIdx.x;
    int c = tid & 63, r4 = tid >> 6;
#pragma unroll
    for (int it = 0; it < 16; ++it) {
        int r = it * 4 + r4;
        tile[r][c] = feat[((size_t)b * T_ + r) * D_ + d0 + c];
    }
    __syncthreads();
#pragma unroll
    for (int it = 0; it < 16; ++it) {
        int r = it * 4 + r4;
        float v = tile[c][r];
        size_t o = ((size_t)b * D_ + d0 + r) * 64 + c;
        fT32[o] = v;
        ushort_t h = f32_to_bf16(v);
        fTh[o] = h;
        fTl[o] = f32_to_bf16(v - bf16_to_f32(h));
    }
}

// ---------- K4: S0[b][t][w] = qw[b][t]·F0[b][w]  (fp32, stored as bf16 hi/lo) ----------
__global__ __launch_bounds__(256) void s0_gemm(
        const float* __restrict__ qw, const float* __restrict__ fT32,
        ushort_t* __restrict__ S0h, ushort_t* __restrict__ S0l) {
    __shared__ float As[64][17];
    __shared__ float Bs[16][65];
    int b = blockIdx.y;
    int t0 = 64 + blockIdx.x * 64;
    int tx = threadIdx.x & 15, ty = threadIdx.x >> 4;
    float acc[4][4] = {};
    for (int k0 = 0; k0 < D_; k0 += 16) {
#pragma unroll
        for (int i = 0; i < 4; ++i) {
            int idx = i * 256 + threadIdx.x;
            int r = idx >> 4, c = idx & 15;
            As[r][c] = qw[((size_t)b * T_ + t0 + r) * D_ + k0 + c];
        }
#pragma unroll
        for (int i = 0; i < 4; ++i) {
            int idx = i * 256 + threadIdx.x;
            int r = idx >> 6, c = idx & 63;
            Bs[r][c] = fT32[((size_t)b * D_ + k0 + r) * 64 + c];
        }
        __syncthreads();
#pragma unroll
        for (int kk = 0; kk < 16; ++kk)
#pragma unroll
            for (int i = 0; i < 4; ++i)
#pragma unroll
                for (int j = 0; j < 4; ++j)
                    acc[i][j] = fmaf(As[ty * 4 + i][kk], Bs[kk][tx * 4 + j], acc[i][j]);
        __syncthreads();
    }
#pragma unroll
    for (int i = 0; i < 4; ++i)
#pragma unroll
        for (int j = 0; j < 4; ++j) {
            float sc = acc[i][j];
            ushort_t h = f32_to_bf16(sc);
            size_t o = ((size_t)b * T_ + t0 + ty * 4 + i) * 64 + tx * 4 + j;
            S0h[o] = h;
            S0l[o] = f32_to_bf16(sc - bf16_to_f32(h));
        }
}

// ---------- K5: sequential core, 1 wave per batch ----------
// u-state X1 in 4x16 register arrays (all constant-indexed -> guaranteed SROA).
// Gamma/C recurrence DEFERRED: alphas stored to LDS; per 16-step sub-block,
// B1 = A_J @ CW (split-bf16 MFMA) + 16-step triangular correction with D[16].
__global__ __launch_bounds__(64, 1) void core_kernel(
        const ushort_t* __restrict__ S0h, const ushort_t* __restrict__ S0l,
        float* __restrict__ gamma) {
    const int b = blockIdx.x;
    const int lane = threadIdx.x;
    const int n16 = lane & 15, quad = lane >> 4;
    __shared__ float ULDS[64 * 67];          // Z: row=pos, col=slot (stride 67, b32 access)
    __shared__ __align__(16) float ALPH[64 * 68];  // alpha matrix: row=step, col=slot
    __shared__ __align__(16) float B1L[16 * 68];   // sub-block Gamma staging
    __shared__ ushort_t CH[64 * 72];         // C rows   [slot][basis]  bf16 hi
    __shared__ ushort_t CL[64 * 72];         //                          bf16 lo
    __shared__ ushort_t CWTh[64 * 72];       // C^T rows [basis][slot]  bf16 hi
    __shared__ ushort_t CWTl[64 * 72];       //                          bf16 lo

#pragma unroll
    for (int jj = 0; jj < 72; ++jj) {
        ushort_t idv = (jj == lane) ? (ushort_t)0x3F80 : (ushort_t)0;
        CH[lane * 72 + jj] = idv;  CL[lane * 72 + jj] = 0;
        CWTh[lane * 72 + jj] = idv; CWTl[lane * 72 + jj] = 0;
    }
    // single wave: DS pipe is in-order per wave; no barriers needed.

#pragma unroll 1
    for (int p = 0; p < 31; ++p) {
        const int t0 = 64 + (p << 6);

        // ---- Lpre = S0sup @ C^T via split-bf16 MFMA -> ULDS ----
        {
            bf16x8 Bh[4][2], Blo[4][2];
#pragma unroll
            for (int nt = 0; nt < 4; ++nt)
#pragma unroll
                for (int kt = 0; kt < 2; ++kt) {
                    int a = (nt * 16 + n16) * 72 + kt * 32 + quad * 8;
                    Bh[nt][kt] = *(const bf16x8*)&CH[a];
                    Blo[nt][kt] = *(const bf16x8*)&CL[a];
                }
#pragma unroll
            for (int mt = 0; mt < 4; ++mt) {
                bf16x8 Ah[2], Alo2[2];
#pragma unroll
                for (int kt = 0; kt < 2; ++kt) {
                    size_t a = ((size_t)b * T_ + t0 + mt * 16 + n16) * 64 + kt * 32 + quad * 8;
                    Ah[kt] = *(const bf16x8*)&S0h[a];
                    Alo2[kt] = *(const bf16x8*)&S0l[a];
                }
                f32x4 acc[4] = {};
#pragma unroll
                for (int nt = 0; nt < 4; ++nt)
#pragma unroll
                    for (int kt = 0; kt < 2; ++kt) {
                        acc[nt] = __builtin_amdgcn_mfma_f32_16x16x32_bf16(Ah[kt], Bh[nt][kt], acc[nt], 0, 0, 0);
                        acc[nt] = __builtin_amdgcn_mfma_f32_16x16x32_bf16(Ah[kt], Blo[nt][kt], acc[nt], 0, 0, 0);
                        acc[nt] = __builtin_amdgcn_mfma_f32_16x16x32_bf16(Alo2[kt], Bh[nt][kt], acc[nt], 0, 0, 0);
                    }
#pragma unroll
                for (int nt = 0; nt < 4; ++nt)
#pragma unroll
                    for (int r = 0; r < 4; ++r)
                        ULDS[(mt * 16 + quad * 4 + r) * 67 + nt * 16 + n16] = acc[nt][r];
            }
        }

        // X1 (lane = time position, index = slot) in 4x16 constant-indexed arrays
        float X1a[16], X1b[16], X1c[16], X1d[16];
#pragma unroll
        for (int l2 = 0; l2 < 16; ++l2) {
            X1a[l2] = ULDS[lane * 67 + l2];
            X1b[l2] = ULDS[lane * 67 + 16 + l2];
            X1c[l2] = ULDS[lane * 67 + 32 + l2];
            X1d[l2] = ULDS[lane * 67 + 48 + l2];
        }
        float lgt = ULDS[lane];  // step-0 logits (row 0, slot=lane)
        float pv = 0.f;

#pragma unroll 1
        for (int j = 0; j < 4; ++j) {
#pragma unroll
            for (int sl = 0; sl < 16; ++sl) {
                const int s = (j << 4) | sl;
                float logit = (lane == s - 1) ? pv : lgt;
                float e = __expf(logit);
                float tot = sum64_dpp(e) + 1.f;  // + exp(0) zero-row
                float alpha = __fdividef(e, tot);
                ALPH[s * 68 + lane] = alpha;
                if (s < 63) lgt = ULDS[(s + 1) * 67 + lane];
                float u0 = 0.f, u1 = 0.f, u2 = 0.f, u3 = 0.f;
                const float4* a4p = (const float4*)&ALPH[s * 68];
#pragma unroll
                for (int i2 = 0; i2 < 4; ++i2) {
                    float4 aa = a4p[i2];
                    u0 = fmaf(aa.x, X1a[4 * i2 + 0], u0);
                    u1 = fmaf(aa.y, X1a[4 * i2 + 1], u1);
                    u2 = fmaf(aa.z, X1a[4 * i2 + 2], u2);
                    u3 = fmaf(aa.w, X1a[4 * i2 + 3], u3);
                    float4 ab = a4p[4 + i2];
                    u0 = fmaf(ab.x, X1b[4 * i2 + 0], u0);
                    u1 = fmaf(ab.y, X1b[4 * i2 + 1], u1);
                    u2 = fmaf(ab.z, X1b[4 * i2 + 2], u2);
                    u3 = fmaf(ab.w, X1b[4 * i2 + 3], u3);
                    float4 ac = a4p[8 + i2];
                    u0 = fmaf(ac.x, X1c[4 * i2 + 0], u0);
                    u1 = fmaf(ac.y, X1c[4 * i2 + 1], u1);
                    u2 = fmaf(ac.z, X1c[4 * i2 + 2], u2);
                    u3 = fmaf(ac.w, X1c[4 * i2 + 3], u3);
                    float4 ad = a4p[12 + i2];
                    u0 = fmaf(ad.x, X1d[4 * i2 + 0], u0);
                    u1 = fmaf(ad.y, X1d[4 * i2 + 1], u1);
                    u2 = fmaf(ad.z, X1d[4 * i2 + 2], u2);
                    u3 = fmaf(ad.w, X1d[4 * i2 + 3], u3);
                }
                float u_new = (u0 + u1) + (u2 + u3);
                if (j == 0) X1a[sl] = u_new;
                else if (j == 1) X1b[sl] = u_new;
                else if (j == 2) X1c[sl] = u_new;
                else X1d[sl] = u_new;
                if (lane > s) ULDS[lane * 67 + s] = u_new;
                if (s < 63) pv = readlane_f(u_new, s + 1);
            }

            // ---- Gamma for sub-block j: B1 = A_J @ CW_preJ (MFMA), then correction ----
            {
                const int J0 = j << 4;
                bf16x8 Aah[2], Aal[2];
#pragma unroll
                for (int kt = 0; kt < 2; ++kt) {
                    float v[8];
                    *(float4*)&v[0] = *(const float4*)&ALPH[(J0 + n16) * 68 + kt * 32 + quad * 8];
                    *(float4*)&v[4] = *(const float4*)&ALPH[(J0 + n16) * 68 + kt * 32 + quad * 8 + 4];
                    bf16x8 h, l;
#pragma unroll
                    for (int i = 0; i < 8; ++i) {
                        ushort_t hh = f32_to_bf16(v[i]);
                        h[i] = (short)hh;
                        l[i] = (short)f32_to_bf16(v[i] - bf16_to_f32(hh));
                    }
                    Aah[kt] = h; Aal[kt] = l;
                }
#pragma unroll
                for (int nt = 0; nt < 4; ++nt) {
                    f32x4 a = {};
#pragma unroll
                    for (int kt = 0; kt < 2; ++kt) {
                        bf16x8 bh = *(const bf16x8*)&CWTh[(nt * 16 + n16) * 72 + kt * 32 + quad * 8];
                        bf16x8 bl = *(const bf16x8*)&CWTl[(nt * 16 + n16) * 72 + kt * 32 + quad * 8];
                        a = __builtin_amdgcn_mfma_f32_16x16x32_bf16(Aah[kt], bh, a, 0, 0, 0);
                        a = __builtin_amdgcn_mfma_f32_16x16x32_bf16(Aah[kt], bl, a, 0, 0, 0);
                        a = __builtin_amdgcn_mfma_f32_16x16x32_bf16(Aal[kt], bh, a, 0, 0, 0);
                    }
#pragma unroll
                    for (int r = 0; r < 4; ++r)
                        B1L[(quad * 4 + r) * 68 + nt * 16 + n16] = a[r];
                }
                // triangular correction sweep (lane = basis column)
                float D[16];
#pragma unroll
                for (int sl = 0; sl < 16; ++sl) {
                    float g = B1L[sl * 68 + lane];
                    const float* arow = &ALPH[(J0 + sl) * 68 + J0];
#pragma unroll
                    for (int c = 0; c < 4; ++c) {
                        if (sl > 4 * c) {
                            float4 am = *(const float4*)&arow[4 * c];
                            if (sl > 4 * c + 0) g = fmaf(am.x, D[4 * c + 0], g);
                            if (sl > 4 * c + 1) g = fmaf(am.y, D[4 * c + 1], g);
                            if (sl > 4 * c + 2) g = fmaf(am.z, D[4 * c + 2], g);
                            if (sl > 4 * c + 3) g = fmaf(am.w, D[4 * c + 3], g);
                        }
                    }
                    const int slot = J0 + sl;
                    float oldv = bf16_to_f32(CH[slot * 72 + lane]) + bf16_to_f32(CL[slot * 72 + lane]);
                    D[sl] = g - oldv;
                    gamma[((size_t)b * T_ + t0 + slot) * 64 + lane] = g;
                    ushort_t gh = f32_to_bf16(g);
                    ushort_t gl2 = f32_to_bf16(g - bf16_to_f32(gh));
                    CH[slot * 72 + lane] = gh;  CL[slot * 72 + lane] = gl2;
                    CWTh[lane * 72 + slot] = gh; CWTl[lane * 72 + slot] = gl2;
                }
            }
        }
    }
}

// ---------- K6: prologue rows 0..63: out = LN(tanh(f)*f + f) ----------
__global__ __launch_bounds__(256) void prologue_kernel(
        const float* __restrict__ feat, float* __restrict__ out,
        const float* __restrict__ lng, const float* __restrict__ lnb) {
    int b = blockIdx.y, t = blockIdx.x, tid = threadIdx.x;
    __shared__ float red[4][2];
    size_t base = ((size_t)b * T_ + t) * D_;
    float4 f4 = *(const float4*)&feat[base + tid * 4];
    float4 y;
    y.x = tanh_fast(f4.x) * f4.x + f4.x;
    y.y = tanh_fast(f4.y) * f4.y + f4.y;
    y.z = tanh_fast(f4.z) * f4.z + f4.z;
    y.w = tanh_fast(f4.w) * f4.w + f4.w;
    float s1 = y.x + y.y + y.z + y.w;
    float s2 = y.x * y.x + y.y * y.y + y.z * y.z + y.w * y.w;
#pragma unroll
    for (int m = 1; m < 64; m <<= 1) { s1 += __shfl_xor(s1, m, 64); s2 += __shfl_xor(s2, m, 64); }
    if ((tid & 63) == 0) { red[tid >> 6][0] = s1; red[tid >> 6][1] = s2; }
    __syncthreads();
    float mu = (red[0][0] + red[1][0] + red[2][0] + red[3][0]) * (1.f / D_);
    float m2 = (red[0][1] + red[1][1] + red[2][1] + red[3][1]) * (1.f / D_);
    float rv = rsqrtf(fmaxf(m2 - mu * mu, 0.f) + LN_EPS);
    float4 g4 = *(const float4*)&lng[tid * 4];
    float4 b4 = *(const float4*)&lnb[tid * 4];
    float4 o;
    o.x = (y.x - mu) * rv * g4.x + b4.x;
    o.y = (y.y - mu) * rv * g4.y + b4.y;
    o.z = (y.z - mu) * rv * g4.z + b4.z;
    o.w = (y.w - mu) * rv * g4.w + b4.w;
    *(float4*)&out[base + tid * 4] = o;
}

// ---------- K7: V = Γ @ F0 (split-bf16 MFMA) fused with gate + LayerNorm ----------
__global__ __launch_bounds__(256) void final_kernel(
        const float* __restrict__ gamma, const ushort_t* __restrict__ fTh,
        const ushort_t* __restrict__ fTl, const float* __restrict__ feat,
        const float* __restrict__ lng, const float* __restrict__ lnb,
        float* __restrict__ out) {
    const int b = blockIdx.y;
    const int t0 = 64 + blockIdx.x * 16;
    const int tid = threadIdx.x, lane = tid & 63, wv = tid >> 6;
    const int n16 = lane & 15, quad = lane >> 4;
    __shared__ float wsum[4][16][2];
    __shared__ float lnp[16][2];

    bf16x8 Ah[2], Alo[2];
    {
        const float* gr = &gamma[((size_t)b * T_ + t0 + n16) * 64];
#pragma unroll
        for (int kt = 0; kt < 2; ++kt) {
            float g[8];
            *(float4*)&g[0] = *(const float4*)&gr[kt * 32 + quad * 8];
            *(float4*)&g[4] = *(const float4*)&gr[kt * 32 + quad * 8 + 4];
            bf16x8 h, l;
#pragma unroll
            for (int i = 0; i < 8; ++i) {
                ushort_t hh = f32_to_bf16(g[i]);
                h[i] = (short)hh;
                l[i] = (short)f32_to_bf16(g[i] - bf16_to_f32(hh));
            }
            Ah[kt] = h; Alo[kt] = l;
        }
    }
    f32x4 acc[16];
#pragma unroll
    for (int j = 0; j < 16; ++j) {
        const int d = wv * 256 + j * 16 + n16;
        const ushort_t* fr = &fTh[((size_t)b * D_ + d) * 64];
        const ushort_t* fr2 = &fTl[((size_t)b * D_ + d) * 64];
        f32x4 a = {0.f, 0.f, 0.f, 0.f};
#pragma unroll
        for (int kt = 0; kt < 2; ++kt) {
            bf16x8 bh = *(const bf16x8*)&fr[kt * 32 + quad * 8];
            bf16x8 bl = *(const bf16x8*)&fr2[kt * 32 + quad * 8];
            a = __builtin_amdgcn_mfma_f32_16x16x32_bf16(Ah[kt], bh, a, 0, 0, 0);
            a = __builtin_amdgcn_mfma_f32_16x16x32_bf16(Ah[kt], bl, a, 0, 0, 0);
            a = __builtin_amdgcn_mfma_f32_16x16x32_bf16(Alo[kt], bh, a, 0, 0, 0);
        }
        acc[j] = a;
    }
    float s1[4] = {0.f, 0.f, 0.f, 0.f}, s2[4] = {0.f, 0.f, 0.f, 0.f};
#pragma unroll
    for (int j = 0; j < 16; ++j) {
        const int d = wv * 256 + j * 16 + n16;
#pragma unroll
        for (int r = 0; r < 4; ++r) {
            float f = feat[((size_t)b * T_ + t0 + quad * 4 + r) * D_ + d];
            float y = tanh_fast(acc[j][r]) * f + f;
            acc[j][r] = y;
            s1[r] += y;
            s2[r] += y * y;
        }
    }
#pragma unroll
    for (int m = 1; m < 16; m <<= 1)
#pragma unroll
        for (int r = 0; r < 4; ++r) { s1[r] += __shfl_xor(s1[r], m, 64); s2[r] += __shfl_xor(s2[r], m, 64); }
    if (n16 == 0) {
#pragma unroll
        for (int r = 0; r < 4; ++r) { wsum[wv][quad * 4 + r][0] = s1[r]; wsum[wv][quad * 4 + r][1] = s2[r]; }
    }
    __syncthreads();
    if (tid < 16) {
        float a = 0.f, c = 0.f;
#pragma unroll
        for (int w2 = 0; w2 < 4; ++w2) { a += wsum[w2][tid][0]; c += wsum[w2][tid][1]; }
        float mu = a * (1.f / D_);
        float var = c * (1.f / D_) - mu * mu;
        lnp[tid][0] = mu;
        lnp[tid][1] = rsqrtf(fmaxf(var, 0.f) + LN_EPS);
    }
    __syncthreads();
#pragma unroll
    for (int j = 0; j < 16; ++j) {
        const int d = wv * 256 + j * 16 + n16;
        float gd = lng[d], bd = lnb[d];
#pragma unroll
        for (int r = 0; r < 4; ++r) {
            int row = quad * 4 + r;
            out[((size_t)b * T_ + t0 + row) * D_ + d] = (acc[j][r] - lnp[row][0]) * lnp[row][1] * gd + bd;
        }
    }
}

extern "C" void kernel_launch(void* const* d_in, const int* in_sizes, int n_in,
                              void* d_out, int out_size, void* d_ws, size_t ws_size,
                              hipStream_t stream) {
    const float* feature = (const float*)d_in[0];
    const float* wq_w    = (const float*)d_in[1];
    const float* wq_b    = (const float*)d_in[2];
    const float* w2_w    = (const float*)d_in[3];
    // d_in[4] = w2_b: softmax-invariant, unused
    const float* ln_g    = (const float*)d_in[5];
    const float* ln_b    = (const float*)d_in[6];
    float* out = (float*)d_out;

    uint8_t* ws = (uint8_t*)d_ws;
    // phase-1 regions
    ushort_t* featbf = (ushort_t*)(ws);                       // 32 MB (dead after gemm_qw)
    ushort_t* wqT    = (ushort_t*)(ws + 32u * 1024 * 1024);   // 2 MB
    // phase-2 regions (alias featbf space)
    float*    gamma = (float*)(ws);                           // 4 MB
    ushort_t* S0h   = (ushort_t*)(ws + 4u * 1024 * 1024);     // 2 MB
    ushort_t* S0l   = (ushort_t*)(ws + 6u * 1024 * 1024);     // 2 MB
    float*    fT32  = (float*)(ws + 8u * 1024 * 1024);        // 2 MB
    ushort_t* fTh   = (ushort_t*)(ws + 10u * 1024 * 1024);    // 1 MB
    ushort_t* fTl   = (ushort_t*)(ws + 11u * 1024 * 1024);    // 1 MB

    const int ntot = B_ * T_ * D_;
    cvt_feat<<<(ntot + 255) / 256, 256, 0, stream>>>(feature, featbf, ntot);
    cvt_wqT<<<dim3(16, 16), 256, 0, stream>>>(wq_w, wqT);
    gemm_qw<<<dim3(128, 16), 256, 0, stream>>>(featbf, wqT, wq_b, w2_w, out);
    featT_kernel<<<dim3(16, 8), 256, 0, stream>>>(feature, fT32, fTh, fTl);
    s0_gemm<<<dim3(31, 8), 256, 0, stream>>>(out, fT32, S0h, S0l);
    core_kernel<<<8, 64, 0, stream>>>(S0h, S0l, gamma);
    prologue_kernel<<<dim3(64, 8), 256, 0, stream>>>(feature, out, ln_g, ln_b);
    final_kernel<<<dim3(124, 8), 256, 0, stream>>>(gamma, fTh, fTl, feature, ln_g, ln_b, out);
}